// Round 3
// baseline (251291.138 us; speedup 1.0000x reference)
//
#include <hip/hip_runtime.h>
#include <hip/hip_bf16.h>

typedef __hip_bfloat16 bf16;
typedef unsigned long long u64;

#define NSTEP 1024
#define BATCH 64
#define HID   512
#define GRID  256
#define NTHR  512

// ---- workspace layout (bytes) ----
// barrier block [0,1024): global@0, xcd[x]@64+64x (x=0..7), rel@576, flag@640
#define OFF_BAR   0u
#define OFF_FLAG  640u
#define OFF_HG    1024u
#define OFF_CG    132096u
#define OFF_GALL  263168u
#define OFF_UCAT  2884608u
#define OFF_WA    23856128u
#define OFF_WM    24904704u
#define OFF_WX    25166848u
#define OFF_BM    25265152u
#define OFF_BX    25273344u
#define OFF_BA    25306112u
#define OFF_YT    25308160u
#define OFF_XT    33696768u

// ---- LDS carve (float indices) ----
// persistent: US[40][516], WML[40][36], HA[8][64*20+8pad]
// HA zone reused: phase-A RED (stride 40), phase-B 2-hop red + MF
// overlay: YA[64][36], XA[8][64][3]; GB[64][40]; LB overlays YA/XA zone
#define L_US    0
#define L_WML   20640
#define L_HA    22080     /* 8 planes x 1288 = 10304 -> ends 32384 */
#define L_YA    32384     /* 64x36 = 2304 -> 34688 */
#define L_XA    34688     /* 1536 -> 36224 */
#define L_GB    36224     /* 2560 -> 38784 */
#define L_LB    32384     /* overlays YA/XA (phase-B only), 9x520=4680 */
#define L_MF    30144     /* L_HA + 8064, 128x12 = 1536 -> 31680 */
#define L_TOT   38784     /* 155136 B < 160 KB */

#define US(c,k)    smem[L_US  + (c)*516 + (k)]
#define WML(c,j)   smem[L_WML + (c)*36  + (j)]
#define HA(q,b,k)  smem[L_HA  + (q)*1288 + (b)*20 + (k)]
#define YA(b,j)    smem[L_YA  + (b)*36 + (j)]
#define XA(a,b,j)  smem[L_XA  + ((a)*64 + (b))*3 + (j)]
#define GB(r,c)    smem[L_GB  + (r)*40 + (c)]
#define LB(j,h)    smem[L_LB  + (j)*520 + (h)]

struct RawIn {
  const void *Y, *x[8];
  const void *W_i,*U_i,*b_i, *W_f,*U_f,*b_f, *W_c,*U_c,*b_c, *W_o,*U_o,*b_o;
  const void *W_ix,*U_ix,*b_ix, *W_cx,*U_cx,*b_cx, *W_a,*b_a;
  float *Ucat,*Wa,*Wm,*Wx,*Bm,*Bx,*Ba,*Yt,*Xt;
  const unsigned *flag;
};

struct Params {
  const float *Ucat,*Wa,*Wm,*Wx,*Bm,*Bx,*Ba,*Yt,*Xt;
  float *Hg,*Cg,*Gall;
  unsigned *bar;
  const unsigned *flag;
  void *out;
};

// ---------------- dtype probe -------------------------------------------------
__global__ void k_detect(const unsigned short* __restrict__ p, unsigned* flag) {
  if (blockIdx.x == 0 && threadIdx.x == 0) {
    int cnt = 0;
    for (int i = 0; i < 64; ++i) {
      unsigned e = (p[i] >> 7) & 0xFF;
      cnt += (e >= 0x60 && e <= 0x7C) || (p[i] & 0x7FFF) == 0;
    }
    *flag = (cnt >= 56) ? 1u : 0u;   // 1 = bf16, 0 = fp32
  }
}

__device__ __forceinline__ float cvt(const void* p, size_t i, bool bf) {
  return bf ? (float)((const bf16*)p)[i] : ((const float*)p)[i];
}

// ---------------- weight normalization ---------------------------------------
#define NWTOT 5605888
__global__ __launch_bounds__(256)
void k_conv_w(RawIn R) {
  const bool bf = (*R.flag) != 0;
  for (size_t i = blockIdx.x*256 + threadIdx.x; i < NWTOT; i += (size_t)gridDim.x*256) {
    if (i < 5242880) {           // Ucat [20][512][512]
      size_t g = i >> 18, r = i & 262143;
      const void* s = g<4 ? (g==0?R.U_i:g==1?R.U_f:g==2?R.U_c:R.U_o)
                    : g<12 ? R.U_ix : R.U_cx;
      size_t off = g<4 ? r : g<12 ? (g-4)*262144 + r : (g-12)*262144 + r;
      R.Ucat[i] = cvt(s, off, bf);
    } else {
      size_t j = i - 5242880;
      if (j < 262144) { R.Wa[j] = cvt(R.W_a, j, bf); }
      else {
        size_t j2 = j - 262144;
        if (j2 < 65536) {        // Wm [4][32][512]
          size_t g = j2 >> 14, r = j2 & 16383;
          const void* s = g==0?R.W_i:g==1?R.W_f:g==2?R.W_c:R.W_o;
          R.Wm[j2] = cvt(s, r, bf);
        } else {
          size_t j3 = j2 - 65536;
          if (j3 < 24576) {      // Wx [16][3][512]
            size_t p = j3 / 1536, r = j3 % 1536;
            R.Wx[j3] = p < 8 ? cvt(R.W_ix, p*1536 + r, bf)
                             : cvt(R.W_cx, (p-8)*1536 + r, bf);
          } else {
            size_t j4 = j3 - 24576;
            if (j4 < 2048) {     // Bm [4][512]
              size_t g = j4 >> 9, c = j4 & 511;
              const void* s = g==0?R.b_i:g==1?R.b_f:g==2?R.b_c:R.b_o;
              R.Bm[j4] = cvt(s, c, bf);
            } else {
              size_t j5 = j4 - 2048;
              if (j5 < 8192) {   // Bx [16][512]
                size_t p = j5 >> 9, c = j5 & 511;
                R.Bx[j5] = p < 8 ? cvt(R.b_ix, p*512 + c, bf)
                                 : cvt(R.b_cx, (p-8)*512 + c, bf);
              } else {
                size_t j6 = j5 - 8192;       // Ba [512]
                R.Ba[j6] = cvt(R.b_a, j6, bf);
              }
            }
          }
        }
      }
    }
  }
}

// ---------------- input normalization (time-major pack) -----------------------
#define NYT 2097152
#define NXT 1572864
__global__ __launch_bounds__(256)
void k_conv_in(RawIn R) {
  const bool bf = (*R.flag) != 0;
  for (size_t i = blockIdx.x*256 + threadIdx.x; i < NYT+NXT; i += (size_t)gridDim.x*256) {
    if (i < NYT) {               // Yt [t][b][32]
      size_t j = i & 31, b = (i >> 5) & 63, t = i >> 11;
      R.Yt[i] = cvt(R.Y, (b*32 + j)*NSTEP + t, bf);
    } else {                     // Xt [t][8][b][3]
      size_t i2 = i - NYT;
      size_t j = i2 % 3, r = i2 / 3;
      size_t b = r & 63; r >>= 6;
      size_t a = r & 7, t = r >> 3;
      R.Xt[i2] = cvt(R.x[a], (b*3 + j)*NSTEP + t, bf);
    }
  }
}

// ---------------- helpers -----------------------------------------------------

__device__ __forceinline__ float sigf(float v){ return 1.f/(1.f+expf(-v)); }

__device__ __forceinline__ float gload(const float* p){
  return __hip_atomic_load(p, __ATOMIC_RELAXED, __HIP_MEMORY_SCOPE_AGENT);
}
__device__ __forceinline__ u64 gload2(const float* p){
  return __hip_atomic_load((const u64*)p, __ATOMIC_RELAXED, __HIP_MEMORY_SCOPE_AGENT);
}
__device__ __forceinline__ void gstore(float* p, float v){
  __hip_atomic_store(p, v, __ATOMIC_RELAXED, __HIP_MEMORY_SCOPE_AGENT);
}
__device__ __forceinline__ void gstore2(float* p, float x, float y){
  union { u64 u_; float f[2]; } v; v.f[0]=x; v.f[1]=y;
  __hip_atomic_store((u64*)p, v.u_, __ATOMIC_RELAXED, __HIP_MEMORY_SCOPE_AGENT);
}

// Fence-free two-level grid barrier. All cross-WG data moves through sc1
// agent-scope relaxed atomics (bypass non-coherent XCD L2), so no L2 flush
// is needed; s_waitcnt vmcnt(0) + s_barrier orders prior sc1 stores first.
// Level 1: 32 WGs RMW their per-XCD line (8 lines in parallel).
// Level 2: 8 leaders RMW the global line. WG0 publishes to the release line.
__device__ __forceinline__ void gbar(unsigned* base, unsigned bi, int w) {
  asm volatile("s_waitcnt vmcnt(0)" ::: "memory");
  __syncthreads();
  if (threadIdx.x == 0) {
    unsigned* xcd  = base + 16 + 16*(w & 7);   // byte 64 + 64*(w&7)
    unsigned* glob = base;                      // byte 0
    unsigned* rel  = base + 144;                // byte 576
    __hip_atomic_fetch_add(xcd, 1u, __ATOMIC_RELAXED, __HIP_MEMORY_SCOPE_AGENT);
    if (w < 8) {
      unsigned* mine = base + 16 + 16*w;
      while (__hip_atomic_load(mine, __ATOMIC_RELAXED, __HIP_MEMORY_SCOPE_AGENT) < bi*32u)
        __builtin_amdgcn_s_sleep(1);
      __hip_atomic_fetch_add(glob, 1u, __ATOMIC_RELAXED, __HIP_MEMORY_SCOPE_AGENT);
    }
    if (w == 0) {
      while (__hip_atomic_load(glob, __ATOMIC_RELAXED, __HIP_MEMORY_SCOPE_AGENT) < bi*8u)
        __builtin_amdgcn_s_sleep(1);
      __hip_atomic_store(rel, bi, __ATOMIC_RELAXED, __HIP_MEMORY_SCOPE_AGENT);
    } else {
      while (__hip_atomic_load(rel, __ATOMIC_RELAXED, __HIP_MEMORY_SCOPE_AGENT) < bi)
        __builtin_amdgcn_s_sleep(2);
    }
  }
  __syncthreads();
}

// ---------------- persistent kernel (grid == #CUs, 512 thr = 8 waves/CU) ------

__global__ __launch_bounds__(NTHR)
void lstm_main(Params P) {
  extern __shared__ float smem[];

  const bool bfout = (*P.flag) != 0;

  const int w   = blockIdx.x;
  const int tid = threadIdx.x;
  // phase A: WG owns 40 unique columns, all 64 rows.
  // 8 cgr x 8 rgr x 8 ksl (ksl == wave id -> wave-uniform k-eighth)
  const int c0  = w * 40;
  const int cgr = tid & 7;          // 8 col groups x 5 cols
  const int rgr = (tid >> 3) & 7;   // 8 row groups; rows rgr + 8*i, i=0..7
  const int ksl = tid >> 6;         // k-eighth (64 k each), one wave each
  const int cl  = cgr * 5;
  // phase B mapping: batch pb, quarter ph0; 32 hg x 4 hp each, 16 kq x 32 k
  const int pb  = w >> 2;
  const int ph0 = (w & 3) * 128;
  const int hg  = tid & 31;
  const int kq  = tid >> 5;

  // ---- one-time init: U strip + per-column input-proj weights into LDS ----
  for (int e = tid; e < 40*512; e += NTHR) {
    int c = e >> 9, k = e & 511;
    int cg = c0 + c, g = cg >> 9, cc = cg & 511;
    US(c, k) = P.Ucat[((size_t)g*HID + k)*HID + cc];
  }
  for (int e = tid; e < 40*36; e += NTHR) {
    int c = e / 36, jj = e % 36;
    int cg = c0 + c, g = cg >> 9, cc = cg & 511;
    float v = 0.f;
    if (jj == 32) {            // bias slot
      v = g < 4  ? P.Bm[g*HID + cc]
        : g < 12 ? P.Bx[(g-4)*HID + cc]
                 : P.Bx[(8 + g-12)*HID + cc];
    } else if (jj < 32 && g < 4) {
      v = P.Wm[((size_t)g*32 + jj)*HID + cc];
    } else if (jj < 3) {
      int p = (g < 12) ? (g-4) : (8 + g-12);
      v = P.Wx[((size_t)p*3 + jj)*HID + cc];
    }
    WML(c, jj) = v;
  }
  __syncthreads();

  unsigned bi = 0;

  // prefetch registers for Hg staging (8 x 8B per thread = one 16-k chunk x 8 eighths)
  u64 pre[8];
  auto hgld = [&](int kcc) {
#pragma unroll
    for (int u = 0; u < 8; ++u) {
      int e2 = tid + u*NTHR;
      int k  = (e2 & 7) * 2;
      int b  = (e2 >> 3) & 63;
      int q  = e2 >> 9;
      pre[u] = gload2(&P.Hg[(size_t)b*HID + q*64 + kcc + k]);
    }
  };

  for (int t = 0; t < NSTEP; ++t) {
    // ===== phase A: z[64][40] = h @ Us (+input proj) -> Gall =====
    for (int e = tid; e < 64*32; e += NTHR) {
      int b = e >> 5, j = e & 31;
      YA(b, j) = P.Yt[((size_t)t*BATCH + b)*32 + j];
    }
    for (int e = tid; e < 8*64*3; e += NTHR) {
      int j2 = e % 3; int r = e / 3; int b = r & 63; int a = r >> 6;
      XA(a, b, j2) = P.Xt[(((size_t)t*8 + a)*BATCH + b)*3 + j2];
    }

    hgld(0);   // issue chunk-0 loads; land under LDS writes

    float acc[8][5];
#pragma unroll
    for (int i=0;i<8;++i)
#pragma unroll
      for (int j=0;j<5;++j) acc[i][j]=0.f;

    const int kb = ksl * 64;
    for (int kc = 0; kc < 64; kc += 16) {    // 4 chunks of 16 k per eighth
      __syncthreads();                       // prev chunk's HA reads done
#pragma unroll
      for (int u = 0; u < 8; ++u) {          // regs -> LDS
        int e2 = tid + u*NTHR;
        int k  = (e2 & 7) * 2;
        int b  = (e2 >> 3) & 63;
        int q  = e2 >> 9;
        union { u64 u_; float f[2]; } v; v.u_ = pre[u];
        float2 t2; t2.x = v.f[0]; t2.y = v.f[1];
        *(float2*)&HA(q, b, k) = t2;
      }
      __syncthreads();
      if (kc + 16 < 64) hgld(kc + 16);       // next chunk in flight over compute

#pragma unroll
      for (int kk = 0; kk < 16; kk += 4) {
        float4 hv[8];
#pragma unroll
        for (int i=0;i<8;++i)
          hv[i] = *(const float4*)&HA(ksl, rgr + 8*i, kk);
#pragma unroll
        for (int j = 0; j < 5; ++j) {
          float4 uv = *(const float4*)&US(cl+j, kb + kc + kk);
#pragma unroll
          for (int i=0;i<8;++i) {
            acc[i][j] += hv[i].x*uv.x; acc[i][j] += hv[i].y*uv.y;
            acc[i][j] += hv[i].z*uv.z; acc[i][j] += hv[i].w*uv.w;
          }
        }
      }
    }

    // ---- k-split reduction (2 hops, overlaying dead HA zone, stride 40) ----
    __syncthreads();                          // all HA reads done before overlay
    if (tid >= 256) {
      float* r = &smem[L_HA + (tid-256)*40];
#pragma unroll
      for (int i=0;i<8;++i)
#pragma unroll
        for (int j=0;j<5;++j) r[i*5+j] = acc[i][j];
    }
    __syncthreads();
    if (tid < 256) {
      const float* r = &smem[L_HA + tid*40];
#pragma unroll
      for (int i=0;i<8;++i)
#pragma unroll
        for (int j=0;j<5;++j) acc[i][j] += r[i*5+j];
    }
    __syncthreads();                          // hop1 reads done before hop2 writes
    if (tid >= 64 && tid < 256) {
      float* r = &smem[L_HA + (tid-64)*40];
#pragma unroll
      for (int i=0;i<8;++i)
#pragma unroll
        for (int j=0;j<5;++j) r[i*5+j] = acc[i][j];
    }
    __syncthreads();
    if (tid < 64) {
#pragma unroll
      for (int q2 = 0; q2 < 3; ++q2) {
        const float* r = &smem[L_HA + (tid + q2*64)*40];
#pragma unroll
        for (int i=0;i<8;++i)
#pragma unroll
          for (int j=0;j<5;++j) acc[i][j] += r[i*5+j];
      }

      // ---- epilogue on wave 0: input projection + bias + nonlinearity ----
      const int col0 = c0 + cl;
      const int gA = col0 >> 9, gB = (col0 + 4) >> 9;
      if (gA == gB && gA < 4) {
        // uniform main-gate fast path: hoisted float4 dot over Y[32]
#pragma unroll
        for (int jb = 0; jb < 8; ++jb) {
          float4 ya[8], wm[5];
#pragma unroll
          for (int i=0;i<8;++i) ya[i] = *(const float4*)&YA(rgr + 8*i, 4*jb);
#pragma unroll
          for (int j=0;j<5;++j) wm[j] = *(const float4*)&WML(cl+j, 4*jb);
#pragma unroll
          for (int i=0;i<8;++i)
#pragma unroll
            for (int j=0;j<5;++j) {
              acc[i][j] += ya[i].x*wm[j].x; acc[i][j] += ya[i].y*wm[j].y;
              acc[i][j] += ya[i].z*wm[j].z; acc[i][j] += ya[i].w*wm[j].w;
            }
        }
#pragma unroll
        for (int i=0;i<8;++i)
#pragma unroll
          for (int j=0;j<5;++j) {
            float v = acc[i][j] + WML(cl+j, 32);
            v = (gA == 2) ? tanhf(v) : sigf(v);
            GB(rgr + 8*i, cl+j) = v;
          }
      } else {
        // per-column path (x-gates and rare mixed-g WGs)
        for (int j = 0; j < 5; ++j) {
          int c = cl + j, cg = c0 + c, g = cg >> 9;
          if (g < 4) {
#pragma unroll
            for (int jb = 0; jb < 8; ++jb) {
              float4 wm = *(const float4*)&WML(c, 4*jb);
#pragma unroll
              for (int i=0;i<8;++i) {
                float4 ya = *(const float4*)&YA(rgr + 8*i, 4*jb);
                acc[i][j] += ya.x*wm.x; acc[i][j] += ya.y*wm.y;
                acc[i][j] += ya.z*wm.z; acc[i][j] += ya.w*wm.w;
              }
            }
#pragma unroll
            for (int i=0;i<8;++i) {
              float v = acc[i][j] + WML(c, 32);
              v = (g == 2) ? tanhf(v) : sigf(v);
              GB(rgr + 8*i, c) = v;
            }
          } else if (g < 12) {
            int p = g-4; int a = (p==0) ? 0 : 1;  // ref quirk: i_x 2..8 all read x2
#pragma unroll
            for (int i=0;i<8;++i) {
              int row = rgr + 8*i;
              float s = WML(c, 32);
              for (int jj = 0; jj < 3; ++jj)
                s += XA(a, row, jj) * WML(c, jj);
              GB(row, c) = sigf(acc[i][j] + s);
            }
          } else {
            int p = g-12;
#pragma unroll
            for (int i=0;i<8;++i) {
              int row = rgr + 8*i;
              float s = WML(c, 32);
              for (int jj = 0; jj < 3; ++jj)
                s += XA(p, row, jj) * WML(c, jj);
              GB(row, c) = tanhf(acc[i][j] + s);
            }
          }
        }
      }
    }
    __syncthreads();
    // cooperative coalesced Gall store: float2, pair never straddles a gate
    for (int e = tid; e < 64*20; e += NTHR) {
      int row = e / 20, p = e % 20;
      int cc2 = c0 + 2*p;
      int g = cc2 >> 9, cc = cc2 & 511;
      gstore2(&P.Gall[((size_t)g*BATCH + row)*HID + cc], GB(row, 2*p), GB(row, 2*p+1));
    }

    gbar(P.bar, ++bi, w);

    // ===== phase B: m = l_all @ W_a, softmax mix, state update =====
    for (int e = tid; e < 9*256; e += NTHR) {   // 8B-wide Gall staging
      int j = e >> 8, h2 = (e & 255) << 1;
      union { u64 u_; float f[2]; } a, b2;
      if (j == 0) {
        a.u_  = gload2(&P.Gall[((size_t)0*BATCH+pb)*HID+h2]);
        b2.u_ = gload2(&P.Gall[((size_t)2*BATCH+pb)*HID+h2]);
      } else {
        int p = j-1;
        a.u_  = gload2(&P.Gall[((size_t)(4+p)*BATCH+pb)*HID+h2]);
        b2.u_ = gload2(&P.Gall[((size_t)(12+p)*BATCH+pb)*HID+h2]);
      }
      float2 t2; t2.x = a.f[0]*b2.f[0]; t2.y = a.f[1]*b2.f[1];
      *(float2*)&LB(j, h2) = t2;
    }
    __syncthreads();

    // each thread: 4 hp cols x 9 j over 32 k; float4 Wa loads (L2-resident)
    float4 a4[9];
#pragma unroll
    for (int j=0;j<9;++j) { a4[j].x=0.f; a4[j].y=0.f; a4[j].z=0.f; a4[j].w=0.f; }
    {
      const int k0 = kq * 32;
      const int hp0 = ph0 + hg*4;
      const float* wa = P.Wa + (size_t)k0*HID + hp0;
#pragma unroll 2
      for (int k = 0; k < 32; k += 4) {
        float4 w0 = *(const float4*)&wa[(size_t)(k+0)*HID];
        float4 w1 = *(const float4*)&wa[(size_t)(k+1)*HID];
        float4 w2 = *(const float4*)&wa[(size_t)(k+2)*HID];
        float4 w3 = *(const float4*)&wa[(size_t)(k+3)*HID];
#pragma unroll
        for (int j=0;j<9;++j) {
          float4 l4 = *(const float4*)&LB(j, k0+k);
          a4[j].x += l4.x*w0.x; a4[j].x += l4.y*w1.x; a4[j].x += l4.z*w2.x; a4[j].x += l4.w*w3.x;
          a4[j].y += l4.x*w0.y; a4[j].y += l4.y*w1.y; a4[j].y += l4.z*w2.y; a4[j].y += l4.w*w3.y;
          a4[j].z += l4.x*w0.z; a4[j].z += l4.y*w1.z; a4[j].z += l4.z*w2.z; a4[j].z += l4.w*w3.z;
          a4[j].w += l4.x*w0.w; a4[j].w += l4.y*w1.w; a4[j].w += l4.z*w2.w; a4[j].w += l4.w*w3.w;
        }
      }
    }
    // 2-hop 16-way reduction in dead HA zone (hop1 stride 40, hop2 stride 36)
    if (tid >= 256) {
      float* r = &smem[L_HA + (tid-256)*40];
#pragma unroll
      for (int j=0;j<9;++j) {
        float* af = (float*)&a4[j];
#pragma unroll
        for (int i=0;i<4;++i) r[j*4+i] = af[i];
      }
    }
    __syncthreads();
    if (tid < 256) {
      const float* r = &smem[L_HA + tid*40];
#pragma unroll
      for (int j=0;j<9;++j) {
        float* af = (float*)&a4[j];
#pragma unroll
        for (int i=0;i<4;++i) af[i] += r[j*4+i];
      }
    }
    __syncthreads();
    if (tid >= 32 && tid < 256) {
      float* r = &smem[L_HA + (tid-32)*36];
#pragma unroll
      for (int j=0;j<9;++j) {
        float* af = (float*)&a4[j];
#pragma unroll
        for (int i=0;i<4;++i) r[j*4+i] = af[i];
      }
    }
    __syncthreads();
    if (tid < 32) {
#pragma unroll
      for (int q2 = 0; q2 < 7; ++q2) {
        const float* r = &smem[L_HA + (tid + q2*32)*36];
#pragma unroll
        for (int j=0;j<9;++j) {
          float* af = (float*)&a4[j];
#pragma unroll
          for (int i=0;i<4;++i) af[i] += r[j*4+i];
        }
      }
      // publish m[hp][9] for the 128 final threads
      float* mf = &smem[L_MF + tid*48];
#pragma unroll
      for (int i=0;i<4;++i)
#pragma unroll
        for (int j=0;j<9;++j) {
          float* af = (float*)&a4[j];
          mf[i*12 + j] = af[i];
        }
    }
    __syncthreads();
    if (tid < 128) {
      const int hp = ph0 + tid;
      const float* mf = &smem[L_MF + tid*12];
      float co = P.Cg[(size_t)pb*HID + hp];
      float ba = P.Ba[hp];
      float u9[9], mx = -1e30f;
#pragma unroll
      for (int j=0;j<9;++j) {
        u9[j] = tanhf(mf[j]*co + ba);
        mx = fmaxf(mx, u9[j]);
      }
      float ssum = 0.f, L = 0.f;
#pragma unroll
      for (int j=0;j<9;++j) {
        float e2 = expf(u9[j]-mx);
        ssum += e2;
        L += e2 * LB(j, hp);
      }
      L /= ssum;
      float f = gload(&P.Gall[((size_t)1*BATCH+pb)*HID + hp]);
      float o = gload(&P.Gall[((size_t)3*BATCH+pb)*HID + hp]);
      float cn = f*co + L;
      float hn = o*tanhf(cn);
      P.Cg[(size_t)pb*HID + hp] = cn;
      gstore(&P.Hg[(size_t)pb*HID + hp], hn);
      size_t iseq = (size_t)BATCH*HID + ((size_t)pb*NSTEP + t)*HID + hp;
      if (bfout) ((bf16*)P.out)[iseq] = __float2bfloat16(hn);
      else       ((float*)P.out)[iseq] = hn;
      if (t == NSTEP-1) {
        size_t ih = (size_t)pb*HID + hp;
        if (bfout) ((bf16*)P.out)[ih] = __float2bfloat16(hn);
        else       ((float*)P.out)[ih] = hn;
      }
    }

    gbar(P.bar, ++bi, w);
  }
}

// ---------------- host entry --------------------------------------------------

extern "C" void kernel_launch(void* const* d_in, const int* in_sizes, int n_in,
                              void* d_out, int out_size, void* d_ws, size_t ws_size,
                              hipStream_t stream) {
  char* ws = (char*)d_ws;

  RawIn R;
  R.Y = d_in[0];
  for (int i = 0; i < 8; ++i) R.x[i] = d_in[1+i];
  R.W_i=d_in[9];  R.U_i=d_in[10]; R.b_i=d_in[11];
  R.W_f=d_in[12]; R.U_f=d_in[13]; R.b_f=d_in[14];
  R.W_c=d_in[15]; R.U_c=d_in[16]; R.b_c=d_in[17];
  R.W_o=d_in[18]; R.U_o=d_in[19]; R.b_o=d_in[20];
  R.W_ix=d_in[21]; R.U_ix=d_in[22]; R.b_ix=d_in[23];
  R.W_cx=d_in[24]; R.U_cx=d_in[25]; R.b_cx=d_in[26];
  R.W_a =d_in[27]; R.b_a =d_in[28];
  R.Ucat=(float*)(ws+OFF_UCAT); R.Wa=(float*)(ws+OFF_WA);
  R.Wm=(float*)(ws+OFF_WM); R.Wx=(float*)(ws+OFF_WX);
  R.Bm=(float*)(ws+OFF_BM); R.Bx=(float*)(ws+OFF_BX); R.Ba=(float*)(ws+OFF_BA);
  R.Yt=(float*)(ws+OFF_YT); R.Xt=(float*)(ws+OFF_XT);
  R.flag=(const unsigned*)(ws+OFF_FLAG);

  Params P;
  P.Ucat=R.Ucat; P.Wa=R.Wa; P.Wm=R.Wm; P.Wx=R.Wx;
  P.Bm=R.Bm; P.Bx=R.Bx; P.Ba=R.Ba; P.Yt=R.Yt; P.Xt=R.Xt;
  P.Hg=(float*)(ws+OFF_HG); P.Cg=(float*)(ws+OFF_CG); P.Gall=(float*)(ws+OFF_GALL);
  P.bar=(unsigned*)(ws+OFF_BAR);
  P.flag=R.flag;
  P.out=d_out;

  // zero barrier block + flag + Hg + Cg (ws is poisoned 0xAA before every call)
  hipMemsetAsync(d_ws, 0, OFF_GALL, stream);

  k_detect<<<1, 64, 0, stream>>>((const unsigned short*)d_in[10], (unsigned*)(ws+OFF_FLAG));
  k_conv_w <<<21899, 256, 0, stream>>>(R);
  k_conv_in<<<14336, 256, 0, stream>>>(R);

  const int smemBytes = L_TOT * 4;   // 155136 B < 160 KB/CU -> 1 WG/CU, 8 waves
  hipFuncSetAttribute((const void*)lstm_main,
                      hipFuncAttributeMaxDynamicSharedMemorySize, smemBytes);
  lstm_main<<<dim3(GRID), dim3(NTHR), smemBytes, stream>>>(P);
}

// Round 4
// 51852.557 us; speedup vs baseline: 4.8463x; 4.8463x over previous
//
#include <hip/hip_runtime.h>
#include <hip/hip_bf16.h>

typedef __hip_bfloat16 bf16;
typedef unsigned long long u64;

#define NSTEP 1024
#define BATCH 64
#define HID   512
#define GRID  256
#define NTHR  512
#define KC    64      // k-chunk per ks-half staged per iteration

// ---- workspace layout (bytes) ----
// barrier block [0,1024): global@0, xcd[x]@64+64x (x=0..7), rel@576, flag@640
#define OFF_BAR   0u
#define OFF_FLAG  640u
#define OFF_HG    1024u
#define OFF_CG    132096u
#define OFF_GALL  263168u
#define OFF_UCAT  2884608u
#define OFF_WA    23856128u
#define OFF_WM    24904704u
#define OFF_WX    25166848u
#define OFF_BM    25265152u
#define OFF_BX    25273344u
#define OFF_BA    25306112u
#define OFF_YT    25308160u
#define OFF_XT    33696768u

// ---- LDS carve (float indices) ----
// persistent: US[40][524], WML[40][36], HA[2][64][68]
// overlay A : YA[64][33], XA[8][64][3], RED[256][11]  (+GB[64][40])
// overlay B : LB[9][520]; phase-B reduction buffers live in dead HA zone
#define L_US    0
#define L_WML   20960
#define L_HA    22400
#define L_YA    31104
#define L_XA    33216
#define L_RED   34752
#define L_GB    36224     /* overlaps RED tail; barrier-separated (RED dead) */
#define L_LB    31104     /* overlays YA/XA (phase-B only), 9x520=4680 */
#define L_RA    22400     /* phase-B hop buf A: 256x19 = 4864 (dead HA zone) */
#define L_RB    27264     /* phase-B hop buf B: 128x19 = 2432 */
#define L_MPZ   29696     /* phase-B final m: 64x19 = 1216 -> ends 30912 */
#define L_TOT   39240     /* 156960 B < 160 KB */

#define US(c,k)    smem[L_US  + (c)*524 + (k)]
#define WML(c,j)   smem[L_WML + (c)*36  + (j)]
#define HA(s,b,k)  smem[L_HA  + (s)*4352 + (b)*68 + (k)]
#define YA(b,j)    smem[L_YA  + (b)*33 + (j)]
#define XA(a,b,j)  smem[L_XA  + ((a)*64 + (b))*3 + (j)]
#define RED(q,j)   smem[L_RED + (q)*11 + (j)]
#define GB(r,c)    smem[L_GB  + (r)*40 + (c)]
#define LB(j,h)    smem[L_LB  + (j)*520 + (h)]

struct RawIn {
  const void *Y, *x[8];
  const void *W_i,*U_i,*b_i, *W_f,*U_f,*b_f, *W_c,*U_c,*b_c, *W_o,*U_o,*b_o;
  const void *W_ix,*U_ix,*b_ix, *W_cx,*U_cx,*b_cx, *W_a,*b_a;
  float *Ucat,*Wa,*Wm,*Wx,*Bm,*Bx,*Ba,*Yt,*Xt;
  const unsigned *flag;
};

struct Params {
  const float *Ucat,*Wa,*Wm,*Wx,*Bm,*Bx,*Ba,*Yt,*Xt;
  float *Hg,*Cg,*Gall;
  unsigned *bar;
  const unsigned *flag;
  void *out;
};

// ---------------- dtype probe -------------------------------------------------
__global__ void k_detect(const unsigned short* __restrict__ p, unsigned* flag) {
  if (blockIdx.x == 0 && threadIdx.x == 0) {
    int cnt = 0;
    for (int i = 0; i < 64; ++i) {
      unsigned e = (p[i] >> 7) & 0xFF;
      cnt += (e >= 0x60 && e <= 0x7C) || (p[i] & 0x7FFF) == 0;
    }
    *flag = (cnt >= 56) ? 1u : 0u;   // 1 = bf16, 0 = fp32
  }
}

__device__ __forceinline__ float cvt(const void* p, size_t i, bool bf) {
  return bf ? (float)((const bf16*)p)[i] : ((const float*)p)[i];
}

// ---------------- weight normalization ---------------------------------------
#define NWTOT 5605888
__global__ __launch_bounds__(256)
void k_conv_w(RawIn R) {
  const bool bf = (*R.flag) != 0;
  for (size_t i = blockIdx.x*256 + threadIdx.x; i < NWTOT; i += (size_t)gridDim.x*256) {
    if (i < 5242880) {           // Ucat [20][512][512]
      size_t g = i >> 18, r = i & 262143;
      const void* s = g<4 ? (g==0?R.U_i:g==1?R.U_f:g==2?R.U_c:R.U_o)
                    : g<12 ? R.U_ix : R.U_cx;
      size_t off = g<4 ? r : g<12 ? (g-4)*262144 + r : (g-12)*262144 + r;
      R.Ucat[i] = cvt(s, off, bf);
    } else {
      size_t j = i - 5242880;
      if (j < 262144) { R.Wa[j] = cvt(R.W_a, j, bf); }
      else {
        size_t j2 = j - 262144;
        if (j2 < 65536) {        // Wm [4][32][512]
          size_t g = j2 >> 14, r = j2 & 16383;
          const void* s = g==0?R.W_i:g==1?R.W_f:g==2?R.W_c:R.W_o;
          R.Wm[j2] = cvt(s, r, bf);
        } else {
          size_t j3 = j2 - 65536;
          if (j3 < 24576) {      // Wx [16][3][512]
            size_t p = j3 / 1536, r = j3 % 1536;
            R.Wx[j3] = p < 8 ? cvt(R.W_ix, p*1536 + r, bf)
                             : cvt(R.W_cx, (p-8)*1536 + r, bf);
          } else {
            size_t j4 = j3 - 24576;
            if (j4 < 2048) {     // Bm [4][512]
              size_t g = j4 >> 9, c = j4 & 511;
              const void* s = g==0?R.b_i:g==1?R.b_f:g==2?R.b_c:R.b_o;
              R.Bm[j4] = cvt(s, c, bf);
            } else {
              size_t j5 = j4 - 2048;
              if (j5 < 8192) {   // Bx [16][512]
                size_t p = j5 >> 9, c = j5 & 511;
                R.Bx[j5] = p < 8 ? cvt(R.b_ix, p*512 + c, bf)
                                 : cvt(R.b_cx, (p-8)*512 + c, bf);
              } else {
                size_t j6 = j5 - 8192;       // Ba [512]
                R.Ba[j6] = cvt(R.b_a, j6, bf);
              }
            }
          }
        }
      }
    }
  }
}

// ---------------- input normalization (time-major pack) -----------------------
#define NYT 2097152
#define NXT 1572864
__global__ __launch_bounds__(256)
void k_conv_in(RawIn R) {
  const bool bf = (*R.flag) != 0;
  for (size_t i = blockIdx.x*256 + threadIdx.x; i < NYT+NXT; i += (size_t)gridDim.x*256) {
    if (i < NYT) {               // Yt [t][b][32]
      size_t j = i & 31, b = (i >> 5) & 63, t = i >> 11;
      R.Yt[i] = cvt(R.Y, (b*32 + j)*NSTEP + t, bf);
    } else {                     // Xt [t][8][b][3]
      size_t i2 = i - NYT;
      size_t j = i2 % 3, r = i2 / 3;
      size_t b = r & 63; r >>= 6;
      size_t a = r & 7, t = r >> 3;
      R.Xt[i2] = cvt(R.x[a], (b*3 + j)*NSTEP + t, bf);
    }
  }
}

// ---------------- helpers -----------------------------------------------------

__device__ __forceinline__ float sigf(float v){ return 1.f/(1.f+expf(-v)); }

__device__ __forceinline__ float gload(const float* p){
  return __hip_atomic_load(p, __ATOMIC_RELAXED, __HIP_MEMORY_SCOPE_AGENT);
}
__device__ __forceinline__ u64 gload2(const float* p){
  return __hip_atomic_load((const u64*)p, __ATOMIC_RELAXED, __HIP_MEMORY_SCOPE_AGENT);
}
__device__ __forceinline__ void gstore(float* p, float v){
  __hip_atomic_store(p, v, __ATOMIC_RELAXED, __HIP_MEMORY_SCOPE_AGENT);
}
__device__ __forceinline__ void gstore2(float* p, float x, float y){
  union { u64 u_; float f[2]; } v; v.f[0]=x; v.f[1]=y;
  __hip_atomic_store((u64*)p, v.u_, __ATOMIC_RELAXED, __HIP_MEMORY_SCOPE_AGENT);
}

// Fence-free two-level grid barrier. All cross-WG data moves through sc1
// agent-scope relaxed atomics (bypass non-coherent XCD L2), so no L2 flush
// is needed; s_waitcnt vmcnt(0) + s_barrier orders prior sc1 stores first.
// Level 1: 32 WGs RMW their per-group line (8 lines in parallel).
// Level 2: 8 leaders RMW the global line. WG0 publishes to the release line.
__device__ __forceinline__ void gbar(unsigned* base, unsigned bi, int w) {
  asm volatile("s_waitcnt vmcnt(0)" ::: "memory");
  __syncthreads();
  if (threadIdx.x == 0) {
    unsigned* xcd  = base + 16 + 16*(w & 7);   // byte 64 + 64*(w&7)
    unsigned* glob = base;                      // byte 0
    unsigned* rel  = base + 144;                // byte 576
    __hip_atomic_fetch_add(xcd, 1u, __ATOMIC_RELAXED, __HIP_MEMORY_SCOPE_AGENT);
    if (w < 8) {
      unsigned* mine = base + 16 + 16*w;
      while (__hip_atomic_load(mine, __ATOMIC_RELAXED, __HIP_MEMORY_SCOPE_AGENT) < bi*32u)
        __builtin_amdgcn_s_sleep(1);
      __hip_atomic_fetch_add(glob, 1u, __ATOMIC_RELAXED, __HIP_MEMORY_SCOPE_AGENT);
    }
    if (w == 0) {
      while (__hip_atomic_load(glob, __ATOMIC_RELAXED, __HIP_MEMORY_SCOPE_AGENT) < bi*8u)
        __builtin_amdgcn_s_sleep(1);
      __hip_atomic_store(rel, bi, __ATOMIC_RELAXED, __HIP_MEMORY_SCOPE_AGENT);
    } else {
      while (__hip_atomic_load(rel, __ATOMIC_RELAXED, __HIP_MEMORY_SCOPE_AGENT) < bi)
        __builtin_amdgcn_s_sleep(2);
    }
  }
  __syncthreads();
}

// ---------------- persistent kernel (grid == #CUs, 512 thr = 8 waves/CU) ------

__global__ __launch_bounds__(NTHR, 2)
void lstm_main(Params P) {
  extern __shared__ float smem[];

  const bool bfout = (*P.flag) != 0;

  const int w   = blockIdx.x;
  const int tid = threadIdx.x;
  // phase A: WG owns 40 unique columns, all 64 rows (R2-proven mapping).
  const int c0  = w * 40;
  const int cgr = tid & 7;          // 8 col groups x 5 cols
  const int rgr = (tid >> 3) & 31;  // 32 row groups; rows rgr, rgr+32
  const int ksl = tid >> 8;         // k-split half (0: k<256, 1: k>=256)
  const int cl  = cgr * 5;
  // phase B mapping: batch pb, quarter ph0; 64 hg x 2 hp, 8-way k-split
  const int pb  = w >> 2;
  const int ph0 = (w & 3) * 128;
  const int hg  = tid & 63;         // hp pair base = ph0 + 2*hg (wave-coalesced)
  const int kq8 = tid >> 6;         // k-eighth 0..7 (wave-uniform -> LB broadcast)

  // ---- one-time init: U strip + per-column input-proj weights into LDS ----
  for (int e = tid; e < 40*512; e += NTHR) {
    int c = e >> 9, k = e & 511;
    int cg = c0 + c, g = cg >> 9, cc = cg & 511;
    US(c, k) = P.Ucat[((size_t)g*HID + k)*HID + cc];
  }
  for (int e = tid; e < 40*33; e += NTHR) {
    int c = e / 33, jj = e % 33;
    int cg = c0 + c, g = cg >> 9, cc = cg & 511;
    float v;
    if (jj == 32) {            // bias slot
      v = g < 4  ? P.Bm[g*HID + cc]
        : g < 12 ? P.Bx[(g-4)*HID + cc]
                 : P.Bx[(8 + g-12)*HID + cc];
    } else if (g < 4) {
      v = P.Wm[((size_t)g*32 + jj)*HID + cc];
    } else if (jj < 3) {
      int p = (g < 12) ? (g-4) : (8 + g-12);
      v = P.Wx[((size_t)p*3 + jj)*HID + cc];
    } else v = 0.f;
    WML(c, jj) = v;
  }
  __syncthreads();

  unsigned bi = 0;

  // prefetch registers for Hg staging (8 x 8B per thread = one 64-k chunk)
  u64 pre[8];
  auto hgld = [&](int kcc) {
#pragma unroll
    for (int u = 0; u < 8; ++u) {
      int e2 = tid + u*NTHR;
      int s2 = e2 >> 11, b = (e2 >> 5) & 63, k = (e2 & 31) * 2;
      pre[u] = gload2(&P.Hg[(size_t)b*HID + s2*256 + kcc + k]);
    }
  };

  for (int t = 0; t < NSTEP; ++t) {
    // ===== phase A: z[64][40] = h @ Us (+input proj) -> Gall =====
    for (int e = tid; e < 64*32; e += NTHR) {
      int b = e >> 5, j = e & 31;
      YA(b, j) = P.Yt[((size_t)t*BATCH + b)*32 + j];
    }
    for (int e = tid; e < 8*64*3; e += NTHR) {
      int j2 = e % 3; int r = e / 3; int b = r & 63; int a = r >> 6;
      XA(a, b, j2) = P.Xt[(((size_t)t*8 + a)*BATCH + b)*3 + j2];
    }

    hgld(0);   // issue chunk-0 loads; land under LDS writes

    float acc[2][5];
#pragma unroll
    for (int i=0;i<2;++i)
#pragma unroll
      for (int j=0;j<5;++j) acc[i][j]=0.f;

    for (int kc = 0; kc < 256; kc += KC) {
      __syncthreads();                       // prev chunk's HA reads done
#pragma unroll
      for (int u = 0; u < 8; ++u) {          // regs -> LDS
        int e2 = tid + u*NTHR;
        int s2 = e2 >> 11, b = (e2 >> 5) & 63, k = (e2 & 31) * 2;
        union { u64 u_; float f[2]; } v; v.u_ = pre[u];
        float2 t2; t2.x = v.f[0]; t2.y = v.f[1];
        *(float2*)&HA(s2, b, k) = t2;
      }
      __syncthreads();
      if (kc + KC < 256) hgld(kc + KC);      // next chunk in flight over compute

      const int kb = ksl*256 + kc;
#pragma unroll 4
      for (int kk = 0; kk < KC; kk += 4) {
        float4 h0 = *(const float4*)&HA(ksl, rgr,      kk);
        float4 h1 = *(const float4*)&HA(ksl, rgr+32,   kk);
#pragma unroll
        for (int j = 0; j < 5; ++j) {
          float4 u = *(const float4*)&US(cl+j, kb+kk);
          acc[0][j] += h0.x*u.x; acc[0][j] += h0.y*u.y;
          acc[0][j] += h0.z*u.z; acc[0][j] += h0.w*u.w;
          acc[1][j] += h1.x*u.x; acc[1][j] += h1.y*u.y;
          acc[1][j] += h1.z*u.z; acc[1][j] += h1.w*u.w;
        }
      }
    }

    // k-split reduction: ksl=1 threads hand partials to ksl=0 partner
    if (ksl) {
      int q = tid - 256;
#pragma unroll
      for (int i=0;i<2;++i)
#pragma unroll
        for (int j=0;j<5;++j) RED(q, i*5+j) = acc[i][j];
    }
    __syncthreads();

    float vv[2][5];
    if (!ksl) {
      // epilogue: input projection + bias + nonlinearity (into registers)
#pragma unroll
      for (int i = 0; i < 2; ++i) {
        int row = rgr + 32*i;
#pragma unroll
        for (int j = 0; j < 5; ++j) {
          int c = cl + j, cg = c0 + c, g = cg >> 9;
          float v = acc[i][j] + RED(tid, i*5+j);
          float s = WML(c, 32);
          if (g < 4) {
            for (int jj = 0; jj < 32; ++jj)
              s += YA(row, jj) * WML(c, jj);
            v += s;
            v = (g==2) ? tanhf(v) : sigf(v);
          } else if (g < 12) {
            int p = g-4; int a = (p==0) ? 0 : 1;  // ref quirk: i_x 2..8 all read x2
            for (int jj = 0; jj < 3; ++jj)
              s += XA(a, row, jj) * WML(c, jj);
            v = sigf(v + s);
          } else {
            int p = g-12;
            for (int jj = 0; jj < 3; ++jj)
              s += XA(p, row, jj) * WML(c, jj);
            v = tanhf(v + s);
          }
          vv[i][j] = v;
        }
      }
    }
    __syncthreads();               // YA/XA reads done before GB overwrites them
    if (!ksl) {
#pragma unroll
      for (int i = 0; i < 2; ++i)
#pragma unroll
        for (int j = 0; j < 5; ++j)
          GB(rgr + 32*i, cl + j) = vv[i][j];
    }
    __syncthreads();
    // cooperative coalesced Gall store: float2, pair never straddles a gate
    for (int e = tid; e < 64*20; e += NTHR) {
      int row = e / 20, p = e % 20;
      int cc2 = c0 + 2*p;
      int g = cc2 >> 9, cc = cc2 & 511;
      gstore2(&P.Gall[((size_t)g*BATCH + row)*HID + cc], GB(row, 2*p), GB(row, 2*p+1));
    }

    gbar(P.bar, ++bi, w);

    // ===== phase B: m = l_all @ W_a, softmax mix, state update =====
    for (int e = tid; e < 9*256; e += NTHR) {   // 8B-wide Gall staging
      int j = e >> 8, h2 = (e & 255) << 1;
      union { u64 u_; float f[2]; } a, b2;
      if (j == 0) {
        a.u_  = gload2(&P.Gall[((size_t)0*BATCH+pb)*HID+h2]);
        b2.u_ = gload2(&P.Gall[((size_t)2*BATCH+pb)*HID+h2]);
      } else {
        int p = j-1;
        a.u_  = gload2(&P.Gall[((size_t)(4+p)*BATCH+pb)*HID+h2]);
        b2.u_ = gload2(&P.Gall[((size_t)(12+p)*BATCH+pb)*HID+h2]);
      }
      float2 t2; t2.x = a.f[0]*b2.f[0]; t2.y = a.f[1]*b2.f[1];
      *(float2*)&LB(j, h2) = t2;
    }
    __syncthreads();

    // each thread: 2 hp cols x 9 j over 64 k; LB reads are wave-broadcast
    // (kq8 wave-uniform), Wa float2 reads wave-coalesced (512B/instr).
    float ab[2][9];
#pragma unroll
    for (int s=0;s<2;++s)
#pragma unroll
      for (int j=0;j<9;++j) ab[s][j]=0.f;
    {
      const int k0 = kq8 * 64;
      const float* wa = P.Wa + (size_t)k0*HID + ph0 + hg*2;
#pragma unroll 4
      for (int k = 0; k < 64; k += 4) {
        float2 w0 = *(const float2*)&wa[(size_t)(k+0)*HID];
        float2 w1 = *(const float2*)&wa[(size_t)(k+1)*HID];
        float2 w2 = *(const float2*)&wa[(size_t)(k+2)*HID];
        float2 w3 = *(const float2*)&wa[(size_t)(k+3)*HID];
#pragma unroll
        for (int j=0;j<9;++j) {
          float4 l4 = *(const float4*)&LB(j, k0+k);
          ab[0][j] += l4.x*w0.x; ab[0][j] += l4.y*w1.x;
          ab[0][j] += l4.z*w2.x; ab[0][j] += l4.w*w3.x;
          ab[1][j] += l4.x*w0.y; ab[1][j] += l4.y*w1.y;
          ab[1][j] += l4.z*w2.y; ab[1][j] += l4.w*w3.y;
        }
      }
    }
    // 8-way k reduction, ping-pong in dead HA zone, stride 19 (conflict-free)
    if (tid >= 256) {                    // hop1 write: kq8 4..7
      float* r = &smem[L_RA + (tid-256)*19];
#pragma unroll
      for (int s=0;s<2;++s)
#pragma unroll
        for (int j=0;j<9;++j) r[s*9+j] = ab[s][j];
    }
    __syncthreads();
    if (tid < 256) {                     // hop1 add; hop2 write: kq8 2..3
      const float* r = &smem[L_RA + tid*19];
#pragma unroll
      for (int s=0;s<2;++s)
#pragma unroll
        for (int j=0;j<9;++j) ab[s][j] += r[s*9+j];
      if (tid >= 128) {
        float* r2 = &smem[L_RB + (tid-128)*19];
#pragma unroll
        for (int s=0;s<2;++s)
#pragma unroll
          for (int j=0;j<9;++j) r2[s*9+j] = ab[s][j];
      }
    }
    __syncthreads();
    if (tid < 128) {                     // hop2 add; hop3 write: kq8 1 (reuse RA)
      const float* r = &smem[L_RB + tid*19];
#pragma unroll
      for (int s=0;s<2;++s)
#pragma unroll
        for (int j=0;j<9;++j) ab[s][j] += r[s*9+j];
      if (tid >= 64) {
        float* r2 = &smem[L_RA + (tid-64)*19];
#pragma unroll
        for (int s=0;s<2;++s)
#pragma unroll
          for (int j=0;j<9;++j) r2[s*9+j] = ab[s][j];
      }
    }
    __syncthreads();
    if (tid < 64) {                      // hop3 add; publish m pairs
      const float* r = &smem[L_RA + tid*19];
      float* mp = &smem[L_MPZ + tid*19];
#pragma unroll
      for (int s=0;s<2;++s)
#pragma unroll
        for (int j=0;j<9;++j) mp[s*9+j] = ab[s][j] + r[s*9+j];
    }
    __syncthreads();
    if (tid < 128) {
      const int hp = ph0 + tid;
      const float* mf = &smem[L_MPZ + (tid>>1)*19 + (tid&1)*9];
      float co = P.Cg[(size_t)pb*HID + hp];
      float ba = P.Ba[hp];
      float u9[9], mx = -1e30f;
#pragma unroll
      for (int j=0;j<9;++j) {
        u9[j] = tanhf(mf[j]*co + ba);
        mx = fmaxf(mx, u9[j]);
      }
      float ssum = 0.f, L = 0.f;
#pragma unroll
      for (int j=0;j<9;++j) {
        float e2 = expf(u9[j]-mx);
        ssum += e2;
        L += e2 * LB(j, hp);
      }
      L /= ssum;
      float f = gload(&P.Gall[((size_t)1*BATCH+pb)*HID + hp]);
      float o = gload(&P.Gall[((size_t)3*BATCH+pb)*HID + hp]);
      float cn = f*co + L;
      float hn = o*tanhf(cn);
      P.Cg[(size_t)pb*HID + hp] = cn;
      gstore(&P.Hg[(size_t)pb*HID + hp], hn);
      size_t iseq = (size_t)BATCH*HID + ((size_t)pb*NSTEP + t)*HID + hp;
      if (bfout) ((bf16*)P.out)[iseq] = __float2bfloat16(hn);
      else       ((float*)P.out)[iseq] = hn;
      if (t == NSTEP-1) {
        size_t ih = (size_t)pb*HID + hp;
        if (bfout) ((bf16*)P.out)[ih] = __float2bfloat16(hn);
        else       ((float*)P.out)[ih] = hn;
      }
    }

    gbar(P.bar, ++bi, w);
  }
}

// ---------------- host entry --------------------------------------------------

extern "C" void kernel_launch(void* const* d_in, const int* in_sizes, int n_in,
                              void* d_out, int out_size, void* d_ws, size_t ws_size,
                              hipStream_t stream) {
  char* ws = (char*)d_ws;

  RawIn R;
  R.Y = d_in[0];
  for (int i = 0; i < 8; ++i) R.x[i] = d_in[1+i];
  R.W_i=d_in[9];  R.U_i=d_in[10]; R.b_i=d_in[11];
  R.W_f=d_in[12]; R.U_f=d_in[13]; R.b_f=d_in[14];
  R.W_c=d_in[15]; R.U_c=d_in[16]; R.b_c=d_in[17];
  R.W_o=d_in[18]; R.U_o=d_in[19]; R.b_o=d_in[20];
  R.W_ix=d_in[21]; R.U_ix=d_in[22]; R.b_ix=d_in[23];
  R.W_cx=d_in[24]; R.U_cx=d_in[25]; R.b_cx=d_in[26];
  R.W_a =d_in[27]; R.b_a =d_in[28];
  R.Ucat=(float*)(ws+OFF_UCAT); R.Wa=(float*)(ws+OFF_WA);
  R.Wm=(float*)(ws+OFF_WM); R.Wx=(float*)(ws+OFF_WX);
  R.Bm=(float*)(ws+OFF_BM); R.Bx=(float*)(ws+OFF_BX); R.Ba=(float*)(ws+OFF_BA);
  R.Yt=(float*)(ws+OFF_YT); R.Xt=(float*)(ws+OFF_XT);
  R.flag=(const unsigned*)(ws+OFF_FLAG);

  Params P;
  P.Ucat=R.Ucat; P.Wa=R.Wa; P.Wm=R.Wm; P.Wx=R.Wx;
  P.Bm=R.Bm; P.Bx=R.Bx; P.Ba=R.Ba; P.Yt=R.Yt; P.Xt=R.Xt;
  P.Hg=(float*)(ws+OFF_HG); P.Cg=(float*)(ws+OFF_CG); P.Gall=(float*)(ws+OFF_GALL);
  P.bar=(unsigned*)(ws+OFF_BAR);
  P.flag=R.flag;
  P.out=d_out;

  // zero barrier block + flag + Hg + Cg (ws is poisoned 0xAA before every call)
  hipMemsetAsync(d_ws, 0, OFF_GALL, stream);

  k_detect<<<1, 64, 0, stream>>>((const unsigned short*)d_in[10], (unsigned*)(ws+OFF_FLAG));
  k_conv_w <<<21899, 256, 0, stream>>>(R);
  k_conv_in<<<14336, 256, 0, stream>>>(R);

  const int smemBytes = L_TOT * 4;   // 156960 B < 160 KB/CU -> 1 WG/CU, 8 waves
  hipFuncSetAttribute((const void*)lstm_main,
                      hipFuncAttributeMaxDynamicSharedMemorySize, smemBytes);
  lstm_main<<<dim3(GRID), dim3(NTHR), smemBytes, stream>>>(P);
}